// Round 8
// baseline (25388.907 us; speedup 1.0000x reference)
//
#include <hip/hip_runtime.h>

#define NBLK 256
#define NTHR 1024

constexpr int H = 1024, MEL = 80, ATT = 640, TXTD = 640, T = 600, TTXT = 128;
constexpr int G4 = 4096, DIN = H + ATT; // 1664
constexpr int QPB = 5;                  // Wq rows owned per score-block (5*128=640)

// ---- workspace layout (floats) ----
constexpr int WS_K     = 0;                  // 128*640
constexpr int WS_V     = WS_K + TTXT * ATT;  // 128*640
constexpr int WS_HV    = WS_V + TTXT * ATT;  // 1024 h_new
constexpr int WS_H0V   = WS_HV + H;          // 1024 h0_new
constexpr int WS_H1V   = WS_H0V + H;         // 1024 h1_new
constexpr int WS_SVP   = WS_H1V + H;         // 8*128 score partial groups
constexpr int WS_GH    = WS_SVP + 8 * TTXT;  // 1
constexpr int WS_DEC   = (WS_GH + 1 + 15) & ~15;        // 160 (conv accum)
constexpr int WS_A0    = (WS_DEC + 2 * MEL + 15) & ~15; // 1024
constexpr int WS_END   = WS_A0 + H;
constexpr int WS_BAR   = (WS_END + 63) & ~63;  // barrier area (u32s)
// barrier: 16 leaf counters 128B apart; epoch at +544 u32 (16 bumps/barrier)

// ---- dynamic LDS layout (floats) ---- (~132.8 KiB — below proven 143.6 KB)
constexpr int SM_W0  = 0;                    // 16*1664 Wih0 rows (grow-mapped)
constexpr int SM_H   = SM_W0 + 16 * DIN;     // 1024 (persists B(t)->A(t+1))
constexpr int SM_H0  = SM_H + H;             // 1024
constexpr int SM_H1  = SM_H0 + H;            // 1024
constexpr int SM_A0  = SM_H1 + H;            // 1024
constexpr int SM_KT  = SM_A0 + H;            // 5*128 K^T slice (b<128)
constexpr int SM_VWL = SM_KT + QPB * TTXT;   // 8 (5 used: own v_w)
constexpr int SM_QL  = SM_VWL + 8;           // 8 (5 used: own q values)
constexpr int SM_OUT = SM_QL + 8;            // 80
constexpr int SM_DEC = SM_OUT + MEL;         // 160
constexpr int SM_RED = SM_DEC + 2 * MEL;     // 16
constexpr int SM_D   = SM_RED + 16;          // 4
constexpr int SM_M   = SM_D + 4 + 8;         // 16*128 M[wave][j]=W0row[H:]·V_j
constexpr int SM_MG  = SM_M + 16 * TTXT;     // 128 Mg[j]=gate_w[H:]·V_j (b0)
constexpr int SM_SV  = SM_MG + TTXT;         // 128 reduced scores
constexpr int SM_CNT = SM_SV + TTXT;
constexpr size_t SM_BYTES = ((size_t)SM_CNT * 4 + 255) & ~(size_t)255;

#define KEEP4(v) \
  asm volatile("" : "+v"((v).x), "+v"((v).y), "+v"((v).z), "+v"((v).w))

struct Params {
  const float *residual, *text, *Wih_a, *Whh_a, *bih_a, *bhh_a,
      *Wq, *Wk, *Wv, *v_w, *Wih0, *Whh0, *bih0, *bhh0,
      *Wih1, *Whh1, *bih1, *bhh1, *D0w, *D0b, *D1w, *D1b,
      *conv_w, *conv_b, *gate_w, *gate_b;
  float* out;
  float* ws;
};

__device__ __forceinline__ float sigm(float x) { return 1.0f / (1.0f + __expf(-x)); }
__device__ __forceinline__ float ftanh(float x) {
  x = fminf(15.f, fmaxf(-15.f, x));
  float e = __expf(2.f * x);
  return (e - 1.f) / (e + 1.f);
}

__device__ __forceinline__ float aload(const float* p) {
  return __hip_atomic_load(p, __ATOMIC_RELAXED, __HIP_MEMORY_SCOPE_AGENT);
}
__device__ __forceinline__ void astore(float* p, float v) {
  __hip_atomic_store(p, v, __ATOMIC_RELAXED, __HIP_MEMORY_SCOPE_AGENT);
}

// Tree split barrier (proven best): arrive = drain vmem + leaf RMW (16 blocks
// per leaf, 128B apart) -> 16th arrival bumps the single epoch word; wait =
// thread 0 polls the hot epoch (efficient broadcast line) with s_sleep.
// Deferred LDS-only work can be placed between arrive and wait.
__device__ __forceinline__ void g_arrive(unsigned* bar) {
  asm volatile("s_waitcnt vmcnt(0)" ::: "memory");
  __syncthreads();
  if (threadIdx.x == 0) {
    unsigned* leaf = bar + (blockIdx.x & 15) * 32;  // 128B apart
    unsigned o = __hip_atomic_fetch_add(leaf, 1u, __ATOMIC_RELAXED,
                                        __HIP_MEMORY_SCOPE_AGENT);
    if ((o & 15) == 15)  // 16 arrivals per leaf -> bump epoch
      __hip_atomic_fetch_add(bar + 544, 1u, __ATOMIC_RELAXED,
                             __HIP_MEMORY_SCOPE_AGENT);
  }
}
__device__ __forceinline__ void g_wait(unsigned* bar, unsigned target) {
  if (threadIdx.x == 0) {
    while (__hip_atomic_load(bar + 544, __ATOMIC_RELAXED,
                             __HIP_MEMORY_SCOPE_AGENT) < target)
      __builtin_amdgcn_s_sleep(1);
  }
  __syncthreads();
}

__device__ __forceinline__ float red64(float s) {
#pragma unroll
  for (int off = 32; off; off >>= 1) s += __shfl_xor(s, off, 64);
  return s;
}

__device__ __forceinline__ float dot16pin(float4 w0, float4 w1, float4 w2,
                                          float4 w3, const float* x, int lane) {
  const float4* x4 = (const float4*)x;
  float4 b0 = x4[lane], b1 = x4[lane + 64], b2 = x4[lane + 128],
         b3 = x4[lane + 192];
  float s0 = w0.x * b0.x, s1 = w1.x * b1.x;
  s0 = fmaf(w0.y, b0.y, s0); s1 = fmaf(w1.y, b1.y, s1);
  s0 = fmaf(w0.z, b0.z, s0); s1 = fmaf(w1.z, b1.z, s1);
  s0 = fmaf(w0.w, b0.w, s0); s1 = fmaf(w1.w, b1.w, s1);
  s0 = fmaf(w2.x, b2.x, s0); s1 = fmaf(w3.x, b3.x, s1);
  s0 = fmaf(w2.y, b2.y, s0); s1 = fmaf(w3.y, b3.y, s1);
  s0 = fmaf(w2.z, b2.z, s0); s1 = fmaf(w3.z, b3.z, s1);
  s0 = fmaf(w2.w, b2.w, s0); s1 = fmaf(w3.w, b3.w, s1);
  return s0 + s1;
}

__device__ __forceinline__ float dot16load(const float* w, const float* x,
                                           int lane) {
  const float4* w4 = (const float4*)w;
  const float4* x4 = (const float4*)x;
  float4 a0 = w4[lane], a1 = w4[lane + 64], a2 = w4[lane + 128],
         a3 = w4[lane + 192];
  float4 b0 = x4[lane], b1 = x4[lane + 64], b2 = x4[lane + 128],
         b3 = x4[lane + 192];
  float s0 = a0.x * b0.x, s1 = a1.x * b1.x;
  s0 = fmaf(a0.y, b0.y, s0); s1 = fmaf(a1.y, b1.y, s1);
  s0 = fmaf(a0.z, b0.z, s0); s1 = fmaf(a1.z, b1.z, s1);
  s0 = fmaf(a0.w, b0.w, s0); s1 = fmaf(a1.w, b1.w, s1);
  s0 = fmaf(a2.x, b2.x, s0); s1 = fmaf(a3.x, b3.x, s1);
  s0 = fmaf(a2.y, b2.y, s0); s1 = fmaf(a3.y, b3.y, s1);
  s0 = fmaf(a2.z, b2.z, s0); s1 = fmaf(a3.z, b3.z, s1);
  s0 = fmaf(a2.w, b2.w, s0); s1 = fmaf(a3.w, b3.w, s1);
  return s0 + s1;
}

__device__ __forceinline__ float wave_dot(const float* __restrict__ w,
                                          const float* __restrict__ x,
                                          int n4, int lane) {
  float s = 0.f;
  const float4* w4 = (const float4*)w;
  const float4* x4 = (const float4*)x;
  for (int i = lane; i < n4; i += 64) {
    float4 a = w4[i];
    float4 b = x4[i];
    s = fmaf(a.x, b.x, s);
    s = fmaf(a.y, b.y, s);
    s = fmaf(a.z, b.z, s);
    s = fmaf(a.w, b.w, s);
  }
  return red64(s);
}

// launch_bounds (NTHR, 2): 128-VGPR budget. LDS (132.8 KB) caps at 1 block/CU
// = 4 waves/SIMD, which HW supports at <=128 VGPR (m69) — the old (NTHR,4)
// 64-VGPR cap forced the 17 pinned float4 weight rows to rematerialize from
// L2 inside every phase, putting L2 latency on each phase's critical path.
__global__ void __launch_bounds__(NTHR, 2) ar_kernel(Params p) {
  const int b = blockIdx.x;
  const int tid = threadIdx.x;
  const int wave = tid >> 6;   // 0..15
  const int lane = tid & 63;
  const int sg = wave >> 2;    // element subgroup 0..3
  const int wg = wave & 3;     // gate / k-chunk within subgroup
  const int gw = b * 16 + wave;  // global wave 0..4095

  float* ws = p.ws;
  float* Kw = ws + WS_K;
  float* Vw = ws + WS_V;
  float* hv = ws + WS_HV;
  float* h0v = ws + WS_H0V;
  float* h1v = ws + WS_H1V;
  float* svp = ws + WS_SVP;
  float* ghp = ws + WS_GH;
  float* dec = ws + WS_DEC;
  float* a0g = ws + WS_A0;
  unsigned* bar = (unsigned*)(ws + WS_BAR);

  extern __shared__ __align__(16) float smem[];
  float* s_w0 = smem + SM_W0;
  float* s_h = smem + SM_H;
  float* s_h0 = smem + SM_H0;
  float* s_h1 = smem + SM_H1;
  float* s_a0 = smem + SM_A0;
  float* s_kt = smem + SM_KT;
  float* s_vwl = smem + SM_VWL;
  float* s_ql = smem + SM_QL;
  float* s_out = smem + SM_OUT;
  float* s_dec = smem + SM_DEC;
  float* s_red = smem + SM_RED;
  float* s_d = smem + SM_D;
  float* s_m = smem + SM_M;
  float* s_mg = smem + SM_MG;
  float* s_sv = smem + SM_SV;

  const int e = 4 * b + sg;
  const int grow = e + wg * H;  // row for phases A(gate), B, D, E

  // ---- invariant weight rows (128-VGPR budget: truly register-resident) ----
  const float4* WA = (const float4*)(p.Whh_a + (size_t)grow * H);
  float4 wa0 = WA[lane], wa1 = WA[lane + 64], wa2 = WA[lane + 128],
         wa3 = WA[lane + 192];
  KEEP4(wa0); KEEP4(wa1); KEEP4(wa2); KEEP4(wa3);
  const float4* W0 = (const float4*)(p.Whh0 + (size_t)grow * H);
  float4 w00 = W0[lane], w01 = W0[lane + 64], w02 = W0[lane + 128],
         w03 = W0[lane + 192];
  KEEP4(w00); KEEP4(w01); KEEP4(w02); KEEP4(w03);
  const float4* W1 = (const float4*)(p.Whh1 + (size_t)grow * H);
  float4 w10 = W1[lane], w11 = W1[lane + 64], w12 = W1[lane + 128],
         w13 = W1[lane + 192];
  KEEP4(w10); KEEP4(w11); KEEP4(w12); KEEP4(w13);
  const float4* WI = (const float4*)(p.Wih1 + (size_t)grow * H);
  float4 wi0 = WI[lane], wi1 = WI[lane + 64], wi2 = WI[lane + 128],
         wi3 = WI[lane + 192];
  KEEP4(wi0); KEEP4(wi1); KEEP4(wi2); KEEP4(wi3);
  float4 wma = make_float4(0.f, 0.f, 0.f, 0.f);
  if (lane < MEL / 4)
    wma = ((const float4*)(p.Wih_a + (size_t)grow * MEL))[lane];
  KEEP4(wma);
  float4 wf = ((const float4*)(p.D0w + (size_t)e * H))[wg * 64 + lane];
  KEEP4(wf);
  float4 wgd = ((const float4*)(p.D1w + (size_t)e * H))[wg * 64 + lane];
  KEEP4(wgd);
  float4 wcv = make_float4(0.f, 0.f, 0.f, 0.f);
  if (tid < 2 * MEL) wcv = ((const float4*)(p.conv_w + (size_t)tid * H))[b];
  KEEP4(wcv);
  const float ba = p.bih_a[grow] + p.bhh_a[grow];
  const float b0s = p.bih0[grow] + p.bhh0[grow];
  const float b1s = p.bih1[grow] + p.bhh1[grow];

  // ---- stage this block's Wih0 rows (grow-mapped) into LDS ----
  {
    const float4* src = (const float4*)(p.Wih0 + (size_t)grow * DIN);
    float4* dst = (float4*)(s_w0 + wave * DIN);
    for (int i = lane; i < DIN / 4; i += 64) dst[i] = src[i];
  }
  if (b < TTXT && tid < QPB) s_vwl[tid] = p.v_w[QPB * b + tid];
  // zero the persistent state vectors (t=0 reads them as prev state)
  s_h[tid] = 0.f;
  s_h0[tid] = 0.f;
  s_h1[tid] = 0.f;

  // block-private LSTM cell states (element 4b+tid, threads 0..3 only)
  float c_reg = 0.f, c0_reg = 0.f, c1_reg = 0.f;
  // per-wave scalars carried between phases (same wave produces & consumes)
  float u0_reg = 0.f, u1_reg = 0.f, w0h_reg = 0.f, pa_reg = 0.f;

  unsigned bk = 0;

  // ---------------- init: precompute K,V (atomic stores) -------------------
  for (int idx = gw; idx < 2 * TTXT * ATT; idx += NBLK * 16) {
    int isV = idx >= TTXT * ATT;
    int rem = isV ? idx - TTXT * ATT : idx;
    int j = rem / ATT;
    int a = rem - j * ATT;
    const float* wrow = (isV ? p.Wv : p.Wk) + a * TXTD;
    float s = wave_dot(wrow, p.text + j * TXTD, TXTD / 4, lane);
    if (lane == 0) astore(&(isV ? Vw : Kw)[j * ATT + a], s);
  }
  if (b == 0)  // zero score-partial accumulators before first use
    for (int i = tid; i < 8 * TTXT; i += NTHR) astore(&svp[i], 0.f);
  g_arrive(bar); ++bk; g_wait(bar, 16 * bk);
  // ---- K^T slice: s_kt[a][d] = K[d][5b+a] for own rows (step-invariant) ---
  if (b < TTXT) {
    for (int i = tid; i < QPB * TTXT; i += NTHR) {
      int a = i >> 7, d = i & (TTXT - 1);
      s_kt[i] = aload(&Kw[d * ATT + QPB * b + a]);
    }
  }
  // ---- precompute M[wave][j] = Wih0[grow, H:]·V_j (step-invariant).
  // ctx is consumed ONLY via dots with Wih0[:,H:] and gate_w[H:], so the
  // softmax-weighted V sum can be pushed through: w0c = sum_j p_j M[j].
  {
    const float4* wrow = (const float4*)(s_w0 + wave * DIN + H);  // 160 f4
    for (int j = 0; j < TTXT; ++j) {
      const float4* v4 = (const float4*)(Vw + j * ATT);
      float s = 0.f;
      for (int i = lane; i < ATT / 4; i += 64) {
        float4 a = wrow[i], x = v4[i];
        s = fmaf(a.x, x.x, s);
        s = fmaf(a.y, x.y, s);
        s = fmaf(a.z, x.z, s);
        s = fmaf(a.w, x.w, s);
      }
      s = red64(s);
      if (lane == 0) s_m[wave * TTXT + j] = s;  // same wave reads it in D
    }
  }
  if (b == 0) {  // Mg[j] = gate_w[H:]·V_j  (read by wave 15 in D-deferred)
    for (int j = wave; j < TTXT; j += 16) {
      float s = wave_dot(p.gate_w + H, Vw + j * ATT, ATT / 4, lane);
      if (lane == 0) s_mg[j] = s;
    }
  }
  __syncthreads();

  // ---------------- main sequential loop (6 barriers/step) ----------------
  for (int t = 0; t < T; ++t) {
    // ---- Phase A: out from dec; attn-LSTM gates. The heavy H-dot was
    //      computed in G(t-1)'s deferred slot (pa_reg); only the 80-wide
    //      out-part remains in-phase. ---------------------------------------
    if (tid < 2 * MEL) s_dec[tid] = aload(dec + tid);
    __syncthreads();
    if (tid < MEL) {
      float o = 0.f;
      if (t != 0) {
        float ls = s_dec[tid] + p.conv_b[tid];
        float bb = s_dec[MEL + tid] + p.conv_b[MEL + tid];
        float r = p.residual[(T - t) * MEL + tid];
        o = (r - bb) * __expf(-ls);
        if (b == 0) p.out[(T - t) * MEL + tid] = o;
      }
      s_out[tid] = o;
    }
    __syncthreads();
    {
      float wred = 0.f;
      if (lane < MEL / 4) {
        float4 bm = ((const float4*)s_out)[lane];
        wred = wma.x * bm.x;
        wred = fmaf(wma.y, bm.y, wred);
        wred = fmaf(wma.z, bm.z, wred);
        wred = fmaf(wma.w, bm.w, wred);
      }
      wred = red64(wred);
      if (lane == 0) s_red[wave] = pa_reg + wred + ba;
      __syncthreads();
      if (tid < 4) {
        int ee = 4 * b + tid;
        float gi = s_red[tid * 4 + 0], gf = s_red[tid * 4 + 1];
        float gg = s_red[tid * 4 + 2], go = s_red[tid * 4 + 3];
        float c2 = sigm(gf) * c_reg + sigm(gi) * ftanh(gg);
        c_reg = c2;
        astore(&hv[ee], sigm(go) * ftanh(c2));
      }
    }
    g_arrive(bar); ++bk;
    g_wait(bar, 16 * bk);

    // ---- Phase B': preload own Wq row / gate_w into regs (hides L2 latency
    //      under the hv gather); stage h; q -> score partials; gate head ----
    {
      float4 qw0, qw1, qw2, qw3;
      const bool qown = (b < TTXT) && (wave < QPB);
      const bool gown = (b == NBLK - 1) && (wave == 15);
      if (qown) {
        const float4* W4 =
            (const float4*)(p.Wq + (size_t)(QPB * b + wave) * H);
        qw0 = W4[lane]; qw1 = W4[lane + 64];
        qw2 = W4[lane + 128]; qw3 = W4[lane + 192];
      } else if (gown) {
        const float4* W4 = (const float4*)p.gate_w;
        qw0 = W4[lane]; qw1 = W4[lane + 64];
        qw2 = W4[lane + 128]; qw3 = W4[lane + 192];
      }
      s_h[tid] = aload(hv + tid);  // persists into A(t+1)
      __syncthreads();
      if (qown) {
        float q = red64(dot16pin(qw0, qw1, qw2, qw3, s_h, lane));
        if (lane == 0) s_ql[wave] = q;
      } else if (gown) {
        float q = red64(dot16pin(qw0, qw1, qw2, qw3, s_h, lane));
        if (lane == 0) astore(&ghp[0], q);
      }
      if (b == NBLK - 1) {
        for (int i = tid; i < 2 * MEL; i += NTHR) astore(&dec[i], 0.f);
      }
      __syncthreads();  // s_ql ready
      if (b < TTXT && tid < TTXT) {
        float partial = 0.f;
#pragma unroll
        for (int a = 0; a < QPB; ++a)
          partial = fmaf(s_vwl[a], ftanh(s_ql[a] + s_kt[a * TTXT + tid]),
                         partial);
        atomicAdd(&svp[(b & 7) * TTXT + tid], partial);  // 16-way contention
      }
    }
    g_arrive(bar); ++bk;
    w0h_reg = red64(dot16load(s_w0 + wave * DIN, s_h, lane));  // deferred
    g_wait(bar, 16 * bk);

    // ---- Phase D: reduce score groups; dec LSTM0 gates via M --------------
    {
      if (tid < TTXT) {
        float s8 = aload(&svp[tid]);
#pragma unroll
        for (int g = 1; g < 8; ++g) s8 += aload(&svp[g * TTXT + tid]);
        s_sv[tid] = s8;
      }
      __syncthreads();
      float pa_ = __expf(s_sv[lane] - 16.f);        // scores bounded ~±11
      float pb_ = __expf(s_sv[lane + 64] - 16.f);
      float den_ = red64(pa_ + pb_);                // all lanes get den
      float w0c = red64(fmaf(pa_, s_m[wave * TTXT + lane],
                             pb_ * s_m[wave * TTXT + lane + 64]));
      if (lane == 0) s_red[wave] = w0c / den_ + w0h_reg + u0_reg + b0s;
      __syncthreads();
      if (tid < 4) {
        int ee = 4 * b + tid;
        float gi = s_red[tid * 4 + 0], gf = s_red[tid * 4 + 1];
        float gg = s_red[tid * 4 + 2], go = s_red[tid * 4 + 3];
        float c2 = sigm(gf) * c0_reg + sigm(gi) * ftanh(gg);
        c0_reg = c2;
        astore(&h0v[ee], sigm(go) * ftanh(c2));
      }
    }
    g_arrive(bar); ++bk;
    if (b == 0 && wave == 15) {  // deferred: gate output via Mg
      float pa_ = __expf(s_sv[lane] - 16.f);
      float pb_ = __expf(s_sv[lane + 64] - 16.f);
      float den_ = red64(pa_ + pb_);
      float gc = red64(fmaf(pa_, s_mg[lane], pb_ * s_mg[lane + 64]));
      if (lane == 0) {
        float gh = aload(&ghp[0]);
        p.out[T * MEL + t] = sigm(gh + gc / den_ + p.gate_b[0]);
      }
    }
    g_wait(bar, 16 * bk);

    // ---- Phase E: dec LSTM1 gates; re-zero svp; (u0' deferred) ------------
    s_h0[tid] = aload(h0v + tid);  // persists (used by deferred u0')
    __syncthreads();
    {
      float pe = dot16pin(wi0, wi1, wi2, wi3, s_h0, lane);
      pe = red64(pe);
      if (lane == 0) s_red[wave] = pe + u1_reg + b1s;
      __syncthreads();
      if (tid < 4) {
        int ee = 4 * b + tid;
        float gi = s_red[tid * 4 + 0], gf = s_red[tid * 4 + 1];
        float gg = s_red[tid * 4 + 2], go = s_red[tid * 4 + 3];
        float c2 = sigm(gf) * c1_reg + sigm(gi) * ftanh(gg);
        c1_reg = c2;
        astore(&h1v[ee], sigm(go) * ftanh(c2));
      }
    }
    if (b == NBLK - 1 && tid < 8 * TTXT)  // svp drained by D; next write B'(t+1)
      astore(&svp[tid], 0.f);
    g_arrive(bar); ++bk;
    u0_reg = red64(dot16pin(w00, w01, w02, w03, s_h0, lane));  // deferred
    g_wait(bar, 16 * bk);

    // ---- Phase F: a0 = tanh(D0w@h1 + b); (u1' for next step deferred) -----
    s_h1[tid] = aload(h1v + tid);
    __syncthreads();
    {
      float4 x = ((const float4*)s_h1)[wg * 64 + lane];
      float s = wf.x * x.x;
      s = fmaf(wf.y, x.y, s); s = fmaf(wf.z, x.z, s); s = fmaf(wf.w, x.w, s);
      s = red64(s);
      if (lane == 0) s_red[wave] = s;
      __syncthreads();
      if (tid < 4) {
        int r2 = 4 * b + tid;
        float tot = s_red[tid * 4] + s_red[tid * 4 + 1] + s_red[tid * 4 + 2] +
                    s_red[tid * 4 + 3];
        astore(&a0g[r2], ftanh(tot + p.D0b[r2]));
      }
    }
    g_arrive(bar); ++bk;
    u1_reg = red64(dot16pin(w10, w11, w12, w13, s_h1, lane));  // deferred
    g_wait(bar, 16 * bk);

    // ---- Phase G: d = tanh(D1w@a0 + b); conv partial into dec;
    //      (A(t+1)'s heavy H-dot deferred under the barrier) ----------------
    s_a0[tid] = aload(a0g + tid);
    __syncthreads();
    {
      float4 x = ((const float4*)s_a0)[wg * 64 + lane];
      float s = wgd.x * x.x;
      s = fmaf(wgd.y, x.y, s); s = fmaf(wgd.z, x.z, s); s = fmaf(wgd.w, x.w, s);
      s = red64(s);
      if (lane == 0) s_red[wave] = s;
      __syncthreads();
      if (tid < 4) {
        int r2 = 4 * b + tid;
        float tot = s_red[tid * 4] + s_red[tid * 4 + 1] + s_red[tid * 4 + 2] +
                    s_red[tid * 4 + 3];
        s_d[tid] = ftanh(tot + p.D1b[r2]);
      }
      __syncthreads();
      if (tid < 2 * MEL) {
        float acc = wcv.x * s_d[0];
        acc = fmaf(wcv.y, s_d[1], acc);
        acc = fmaf(wcv.z, s_d[2], acc);
        acc = fmaf(wcv.w, s_d[3], acc);
        atomicAdd(&dec[tid], acc);
      }
    }
    g_arrive(bar); ++bk;
    pa_reg = red64(dot16pin(wa0, wa1, wa2, wa3, s_h, lane));  // for A(t+1)
    g_wait(bar, 16 * bk);
  }

  // ---- epilogue: output for t = T-1 (total[0]) ----
  if (b == 0 && tid < MEL) {
    float ls = aload(&dec[tid]) + p.conv_b[tid];
    float bb = aload(&dec[MEL + tid]) + p.conv_b[MEL + tid];
    float r = p.residual[tid];
    p.out[tid] = (r - bb) * __expf(-ls);
  }
}

extern "C" void kernel_launch(void* const* d_in, const int* in_sizes, int n_in,
                              void* d_out, int out_size, void* d_ws, size_t ws_size,
                              hipStream_t stream) {
  Params hp;
  hp.residual = (const float*)d_in[0];
  hp.text = (const float*)d_in[1];
  hp.Wih_a = (const float*)d_in[2];
  hp.Whh_a = (const float*)d_in[3];
  hp.bih_a = (const float*)d_in[4];
  hp.bhh_a = (const float*)d_in[5];
  hp.Wq = (const float*)d_in[6];
  hp.Wk = (const float*)d_in[7];
  hp.Wv = (const float*)d_in[8];
  hp.v_w = (const float*)d_in[9];
  hp.Wih0 = (const float*)d_in[10];
  hp.Whh0 = (const float*)d_in[11];
  hp.bih0 = (const float*)d_in[12];
  hp.bhh0 = (const float*)d_in[13];
  hp.Wih1 = (const float*)d_in[14];
  hp.Whh1 = (const float*)d_in[15];
  hp.bih1 = (const float*)d_in[16];
  hp.bhh1 = (const float*)d_in[17];
  hp.D0w = (const float*)d_in[18];
  hp.D0b = (const float*)d_in[19];
  hp.D1w = (const float*)d_in[20];
  hp.D1b = (const float*)d_in[21];
  hp.conv_w = (const float*)d_in[22];
  hp.conv_b = (const float*)d_in[23];
  hp.gate_w = (const float*)d_in[24];
  hp.gate_b = (const float*)d_in[25];
  hp.out = (float*)d_out;
  hp.ws = (float*)d_ws;

  hipMemsetAsync((char*)d_ws + (size_t)WS_BAR * sizeof(float), 0, 4096, stream);

  void* args[] = {&hp};
  hipLaunchCooperativeKernel((void*)ar_kernel, dim3(NBLK), dim3(NTHR), args,
                             (uint32_t)SM_BYTES, stream);
}

// Round 9
// 22499.167 us; speedup vs baseline: 1.1284x; 1.1284x over previous
//
#include <hip/hip_runtime.h>

#define NBLK 256
#define NTHR 1024

constexpr int H = 1024, MEL = 80, ATT = 640, TXTD = 640, T = 600, TTXT = 128;
constexpr int G4 = 4096, DIN = H + ATT; // 1664
constexpr int QPB = 5;                  // Wq rows owned per score-block (5*128=640)

// ---- workspace layout (floats) ----
constexpr int WS_K     = 0;                  // 128*640
constexpr int WS_V     = WS_K + TTXT * ATT;  // 128*640
constexpr int WS_HV    = WS_V + TTXT * ATT;  // 1024 h_new
constexpr int WS_H0V   = WS_HV + H;          // 1024 h0_new
constexpr int WS_H1V   = WS_H0V + H;         // 1024 h1_new
constexpr int WS_SVP   = WS_H1V + H;         // 8*128 score partial groups
constexpr int WS_GH    = WS_SVP + 8 * TTXT;  // 1
constexpr int WS_DEC   = (WS_GH + 1 + 15) & ~15;        // 160 (conv accum)
constexpr int WS_A0    = (WS_DEC + 2 * MEL + 15) & ~15; // 1024
constexpr int WS_END   = WS_A0 + H;
constexpr int WS_BAR   = (WS_END + 63) & ~63;  // barrier area (u32s)
// barrier: 16 leaf counters 128B apart; epoch at +544 u32 (16 bumps/barrier)

// ---- dynamic LDS layout (floats) ---- (~132.8 KiB — below proven 143.6 KB)
constexpr int SM_W0  = 0;                    // 16*1664 Wih0 rows (grow-mapped)
constexpr int SM_H   = SM_W0 + 16 * DIN;     // 1024 (persists B(t)->A(t+1))
constexpr int SM_H0  = SM_H + H;             // 1024
constexpr int SM_H1  = SM_H0 + H;            // 1024
constexpr int SM_A0  = SM_H1 + H;            // 1024
constexpr int SM_KT  = SM_A0 + H;            // 5*128 K^T slice (b<128)
constexpr int SM_VWL = SM_KT + QPB * TTXT;   // 8 (5 used: own v_w)
constexpr int SM_QL  = SM_VWL + 8;           // 8 (5 used: own q values)
constexpr int SM_OUT = SM_QL + 8;            // 80
constexpr int SM_DEC = SM_OUT + MEL;         // 160
constexpr int SM_RED = SM_DEC + 2 * MEL;     // 16
constexpr int SM_D   = SM_RED + 16;          // 4
constexpr int SM_M   = SM_D + 4 + 8;         // 16*128 M[wave][j]=W0row[H:]·V_j
constexpr int SM_MG  = SM_M + 16 * TTXT;     // 128 Mg[j]=gate_w[H:]·V_j (b0)
constexpr int SM_SV  = SM_MG + TTXT;         // 128 reduced scores
constexpr int SM_CNT = SM_SV + TTXT;
constexpr size_t SM_BYTES = ((size_t)SM_CNT * 4 + 255) & ~(size_t)255;

struct Params {
  const float *residual, *text, *Wih_a, *Whh_a, *bih_a, *bhh_a,
      *Wq, *Wk, *Wv, *v_w, *Wih0, *Whh0, *bih0, *bhh0,
      *Wih1, *Whh1, *bih1, *bhh1, *D0w, *D0b, *D1w, *D1b,
      *conv_w, *conv_b, *gate_w, *gate_b;
  float* out;
  float* ws;
};

__device__ __forceinline__ float sigm(float x) { return 1.0f / (1.0f + __expf(-x)); }
__device__ __forceinline__ float ftanh(float x) {
  x = fminf(15.f, fmaxf(-15.f, x));
  float e = __expf(2.f * x);
  return (e - 1.f) / (e + 1.f);
}

__device__ __forceinline__ float aload(const float* p) {
  return __hip_atomic_load(p, __ATOMIC_RELAXED, __HIP_MEMORY_SCOPE_AGENT);
}
__device__ __forceinline__ void astore(float* p, float v) {
  __hip_atomic_store(p, v, __ATOMIC_RELAXED, __HIP_MEMORY_SCOPE_AGENT);
}

// Volatile weight load: the compiler CANNOT rematerialize (re-execute) a
// volatile load, so the loaded values must stay live in registers for the
// whole kernel (VGPR_Count=64 in r7/r8 proved KEEP4-pinning was being
// silently rematerialized from L2/LLC inside every phase — ~21 MB/step of
// FETCH traffic on each phase's critical path).
__device__ __forceinline__ float4 vload4(const float* p) {
  volatile const float* q = p;
  float4 r;
  r.x = q[0]; r.y = q[1]; r.z = q[2]; r.w = q[3];
  return r;
}

// Tree split barrier (proven best): arrive = drain vmem + leaf RMW (16 blocks
// per leaf, 128B apart) -> 16th arrival bumps the single epoch word; wait =
// thread 0 polls the hot epoch (efficient broadcast line) with s_sleep.
// Deferred LDS-only work can be placed between arrive and wait.
__device__ __forceinline__ void g_arrive(unsigned* bar) {
  asm volatile("s_waitcnt vmcnt(0)" ::: "memory");
  __syncthreads();
  if (threadIdx.x == 0) {
    unsigned* leaf = bar + (blockIdx.x & 15) * 32;  // 128B apart
    unsigned o = __hip_atomic_fetch_add(leaf, 1u, __ATOMIC_RELAXED,
                                        __HIP_MEMORY_SCOPE_AGENT);
    if ((o & 15) == 15)  // 16 arrivals per leaf -> bump epoch
      __hip_atomic_fetch_add(bar + 544, 1u, __ATOMIC_RELAXED,
                             __HIP_MEMORY_SCOPE_AGENT);
  }
}
__device__ __forceinline__ void g_wait(unsigned* bar, unsigned target) {
  if (threadIdx.x == 0) {
    while (__hip_atomic_load(bar + 544, __ATOMIC_RELAXED,
                             __HIP_MEMORY_SCOPE_AGENT) < target)
      __builtin_amdgcn_s_sleep(1);
  }
  __syncthreads();
}

__device__ __forceinline__ float red64(float s) {
#pragma unroll
  for (int off = 32; off; off >>= 1) s += __shfl_xor(s, off, 64);
  return s;
}

__device__ __forceinline__ float dot16pin(float4 w0, float4 w1, float4 w2,
                                          float4 w3, const float* x, int lane) {
  const float4* x4 = (const float4*)x;
  float4 b0 = x4[lane], b1 = x4[lane + 64], b2 = x4[lane + 128],
         b3 = x4[lane + 192];
  float s0 = w0.x * b0.x, s1 = w1.x * b1.x;
  s0 = fmaf(w0.y, b0.y, s0); s1 = fmaf(w1.y, b1.y, s1);
  s0 = fmaf(w0.z, b0.z, s0); s1 = fmaf(w1.z, b1.z, s1);
  s0 = fmaf(w0.w, b0.w, s0); s1 = fmaf(w1.w, b1.w, s1);
  s0 = fmaf(w2.x, b2.x, s0); s1 = fmaf(w3.x, b3.x, s1);
  s0 = fmaf(w2.y, b2.y, s0); s1 = fmaf(w3.y, b3.y, s1);
  s0 = fmaf(w2.z, b2.z, s0); s1 = fmaf(w3.z, b3.z, s1);
  s0 = fmaf(w2.w, b2.w, s0); s1 = fmaf(w3.w, b3.w, s1);
  return s0 + s1;
}

__device__ __forceinline__ float dot16load(const float* w, const float* x,
                                           int lane) {
  const float4* w4 = (const float4*)w;
  const float4* x4 = (const float4*)x;
  float4 a0 = w4[lane], a1 = w4[lane + 64], a2 = w4[lane + 128],
         a3 = w4[lane + 192];
  float4 b0 = x4[lane], b1 = x4[lane + 64], b2 = x4[lane + 128],
         b3 = x4[lane + 192];
  float s0 = a0.x * b0.x, s1 = a1.x * b1.x;
  s0 = fmaf(a0.y, b0.y, s0); s1 = fmaf(a1.y, b1.y, s1);
  s0 = fmaf(a0.z, b0.z, s0); s1 = fmaf(a1.z, b1.z, s1);
  s0 = fmaf(a0.w, b0.w, s0); s1 = fmaf(a1.w, b1.w, s1);
  s0 = fmaf(a2.x, b2.x, s0); s1 = fmaf(a3.x, b3.x, s1);
  s0 = fmaf(a2.y, b2.y, s0); s1 = fmaf(a3.y, b3.y, s1);
  s0 = fmaf(a2.z, b2.z, s0); s1 = fmaf(a3.z, b3.z, s1);
  s0 = fmaf(a2.w, b2.w, s0); s1 = fmaf(a3.w, b3.w, s1);
  return s0 + s1;
}

__device__ __forceinline__ float wave_dot(const float* __restrict__ w,
                                          const float* __restrict__ x,
                                          int n4, int lane) {
  float s = 0.f;
  const float4* w4 = (const float4*)w;
  const float4* x4 = (const float4*)x;
  for (int i = lane; i < n4; i += 64) {
    float4 a = w4[i];
    float4 b = x4[i];
    s = fmaf(a.x, b.x, s);
    s = fmaf(a.y, b.y, s);
    s = fmaf(a.z, b.z, s);
    s = fmaf(a.w, b.w, s);
  }
  return red64(s);
}

// launch_bounds (NTHR, 2): 256-VGPR budget so the ~80 volatile-pinned weight
// VGPRs live in registers (not scratch). LDS (132.8 KB) caps occupancy at
// 1 block/CU = 4 waves/SIMD regardless, so the larger register budget costs
// no occupancy.
__global__ void __launch_bounds__(NTHR, 2) ar_kernel(Params p) {
  const int b = blockIdx.x;
  const int tid = threadIdx.x;
  const int wave = tid >> 6;   // 0..15
  const int lane = tid & 63;
  const int sg = wave >> 2;    // element subgroup 0..3
  const int wg = wave & 3;     // gate / k-chunk within subgroup
  const int gw = b * 16 + wave;  // global wave 0..4095

  float* ws = p.ws;
  float* Kw = ws + WS_K;
  float* Vw = ws + WS_V;
  float* hv = ws + WS_HV;
  float* h0v = ws + WS_H0V;
  float* h1v = ws + WS_H1V;
  float* svp = ws + WS_SVP;
  float* ghp = ws + WS_GH;
  float* dec = ws + WS_DEC;
  float* a0g = ws + WS_A0;
  unsigned* bar = (unsigned*)(ws + WS_BAR);

  extern __shared__ __align__(16) float smem[];
  float* s_w0 = smem + SM_W0;
  float* s_h = smem + SM_H;
  float* s_h0 = smem + SM_H0;
  float* s_h1 = smem + SM_H1;
  float* s_a0 = smem + SM_A0;
  float* s_kt = smem + SM_KT;
  float* s_vwl = smem + SM_VWL;
  float* s_ql = smem + SM_QL;
  float* s_out = smem + SM_OUT;
  float* s_dec = smem + SM_DEC;
  float* s_red = smem + SM_RED;
  float* s_d = smem + SM_D;
  float* s_m = smem + SM_M;
  float* s_mg = smem + SM_MG;
  float* s_sv = smem + SM_SV;

  const int e = 4 * b + sg;
  const int grow = e + wg * H;  // row for phases A(gate), B, D, E

  // ---- invariant weight rows: volatile loads -> MUST stay register-resident
  const float* WA = p.Whh_a + (size_t)grow * H;
  float4 wa0 = vload4(WA + 4 * lane), wa1 = vload4(WA + 4 * (lane + 64)),
         wa2 = vload4(WA + 4 * (lane + 128)), wa3 = vload4(WA + 4 * (lane + 192));
  const float* W0 = p.Whh0 + (size_t)grow * H;
  float4 w00 = vload4(W0 + 4 * lane), w01 = vload4(W0 + 4 * (lane + 64)),
         w02 = vload4(W0 + 4 * (lane + 128)), w03 = vload4(W0 + 4 * (lane + 192));
  const float* W1 = p.Whh1 + (size_t)grow * H;
  float4 w10 = vload4(W1 + 4 * lane), w11 = vload4(W1 + 4 * (lane + 64)),
         w12 = vload4(W1 + 4 * (lane + 128)), w13 = vload4(W1 + 4 * (lane + 192));
  const float* WI = p.Wih1 + (size_t)grow * H;
  float4 wi0 = vload4(WI + 4 * lane), wi1 = vload4(WI + 4 * (lane + 64)),
         wi2 = vload4(WI + 4 * (lane + 128)), wi3 = vload4(WI + 4 * (lane + 192));
  float4 wma = make_float4(0.f, 0.f, 0.f, 0.f);
  if (lane < MEL / 4)
    wma = vload4(p.Wih_a + (size_t)grow * MEL + 4 * lane);
  float4 wf = vload4(p.D0w + (size_t)e * H + 4 * (wg * 64 + lane));
  float4 wgd = vload4(p.D1w + (size_t)e * H + 4 * (wg * 64 + lane));
  float4 wcv = make_float4(0.f, 0.f, 0.f, 0.f);
  if (tid < 2 * MEL) wcv = vload4(p.conv_w + (size_t)tid * H + 4 * b);
  const float ba = p.bih_a[grow] + p.bhh_a[grow];
  const float b0s = p.bih0[grow] + p.bhh0[grow];
  const float b1s = p.bih1[grow] + p.bhh1[grow];

  // ---- stage this block's Wih0 rows (grow-mapped) into LDS ----
  {
    const float4* src = (const float4*)(p.Wih0 + (size_t)grow * DIN);
    float4* dst = (float4*)(s_w0 + wave * DIN);
    for (int i = lane; i < DIN / 4; i += 64) dst[i] = src[i];
  }
  if (b < TTXT && tid < QPB) s_vwl[tid] = p.v_w[QPB * b + tid];
  // zero the persistent state vectors (t=0 reads them as prev state)
  s_h[tid] = 0.f;
  s_h0[tid] = 0.f;
  s_h1[tid] = 0.f;

  // block-private LSTM cell states (element 4b+tid, threads 0..3 only)
  float c_reg = 0.f, c0_reg = 0.f, c1_reg = 0.f;
  // per-wave scalars carried between phases (same wave produces & consumes)
  float u0_reg = 0.f, u1_reg = 0.f, w0h_reg = 0.f;

  unsigned bk = 0;

  // ---------------- init: precompute K,V (atomic stores) -------------------
  for (int idx = gw; idx < 2 * TTXT * ATT; idx += NBLK * 16) {
    int isV = idx >= TTXT * ATT;
    int rem = isV ? idx - TTXT * ATT : idx;
    int j = rem / ATT;
    int a = rem - j * ATT;
    const float* wrow = (isV ? p.Wv : p.Wk) + a * TXTD;
    float s = wave_dot(wrow, p.text + j * TXTD, TXTD / 4, lane);
    if (lane == 0) astore(&(isV ? Vw : Kw)[j * ATT + a], s);
  }
  if (b == 0)  // zero score-partial accumulators before first use
    for (int i = tid; i < 8 * TTXT; i += NTHR) astore(&svp[i], 0.f);
  g_arrive(bar); ++bk; g_wait(bar, 16 * bk);
  // ---- K^T slice: s_kt[a][d] = K[d][5b+a] for own rows (step-invariant) ---
  if (b < TTXT) {
    for (int i = tid; i < QPB * TTXT; i += NTHR) {
      int a = i >> 7, d = i & (TTXT - 1);
      s_kt[i] = aload(&Kw[d * ATT + QPB * b + a]);
    }
  }
  // ---- precompute M[wave][j] = Wih0[grow, H:]·V_j (step-invariant).
  // ctx is consumed ONLY via dots with Wih0[:,H:] and gate_w[H:], so the
  // softmax-weighted V sum can be pushed through: w0c = sum_j p_j M[j].
  {
    const float4* wrow = (const float4*)(s_w0 + wave * DIN + H);  // 160 f4
    for (int j = 0; j < TTXT; ++j) {
      const float4* v4 = (const float4*)(Vw + j * ATT);
      float s = 0.f;
      for (int i = lane; i < ATT / 4; i += 64) {
        float4 a = wrow[i], x = v4[i];
        s = fmaf(a.x, x.x, s);
        s = fmaf(a.y, x.y, s);
        s = fmaf(a.z, x.z, s);
        s = fmaf(a.w, x.w, s);
      }
      s = red64(s);
      if (lane == 0) s_m[wave * TTXT + j] = s;  // same wave reads it in D
    }
  }
  if (b == 0) {  // Mg[j] = gate_w[H:]·V_j  (read by wave 15 in D-deferred)
    for (int j = wave; j < TTXT; j += 16) {
      float s = wave_dot(p.gate_w + H, Vw + j * ATT, ATT / 4, lane);
      if (lane == 0) s_mg[j] = s;
    }
  }
  __syncthreads();

  // ---------------- main sequential loop (6 barriers/step) ----------------
  for (int t = 0; t < T; ++t) {
    // ---- Phase A: out from dec; attn-LSTM gates (s_h persisted from B) ----
    if (tid < 2 * MEL) s_dec[tid] = aload(dec + tid);
    __syncthreads();
    if (tid < MEL) {
      float o = 0.f;
      if (t != 0) {
        float ls = s_dec[tid] + p.conv_b[tid];
        float bb = s_dec[MEL + tid] + p.conv_b[MEL + tid];
        float r = p.residual[(T - t) * MEL + tid];
        o = (r - bb) * __expf(-ls);
        if (b == 0) p.out[(T - t) * MEL + tid] = o;
      }
      s_out[tid] = o;
    }
    __syncthreads();
    {
      float pa = dot16pin(wa0, wa1, wa2, wa3, s_h, lane);
      if (lane < MEL / 4) {
        float4 bm = ((const float4*)s_out)[lane];
        pa = fmaf(wma.x, bm.x, pa);
        pa = fmaf(wma.y, bm.y, pa);
        pa = fmaf(wma.z, bm.z, pa);
        pa = fmaf(wma.w, bm.w, pa);
      }
      pa = red64(pa);
      if (lane == 0) s_red[wave] = pa + ba;
      __syncthreads();
      if (tid < 4) {
        int ee = 4 * b + tid;
        float gi = s_red[tid * 4 + 0], gf = s_red[tid * 4 + 1];
        float gg = s_red[tid * 4 + 2], go = s_red[tid * 4 + 3];
        float c2 = sigm(gf) * c_reg + sigm(gi) * ftanh(gg);
        c_reg = c2;
        astore(&hv[ee], sigm(go) * ftanh(c2));
      }
    }
    g_arrive(bar); ++bk;
    g_wait(bar, 16 * bk);

    // ---- Phase B': stage h; own q rows (streamed Wq) -> score partials
    //      (fused old B+C); gate head on block 255; (w0h deferred) ----------
    s_h[tid] = aload(hv + tid);  // persists into A(t+1)
    __syncthreads();
    if (b < TTXT && wave < QPB) {
      float q = red64(
          dot16load(p.Wq + (size_t)(QPB * b + wave) * H, s_h, lane));
      if (lane == 0) s_ql[wave] = q;
    }
    if (b == NBLK - 1) {
      if (wave == 15) {  // gate head: gate_w[0:H]·h (streamed, L2-resident)
        float q = wave_dot(p.gate_w, s_h, H / 4, lane);
        if (lane == 0) astore(&ghp[0], q);
      }
      for (int i = tid; i < 2 * MEL; i += NTHR) astore(&dec[i], 0.f);
    }
    __syncthreads();  // s_ql ready
    if (b < TTXT && tid < TTXT) {
      float partial = 0.f;
#pragma unroll
      for (int a = 0; a < QPB; ++a)
        partial = fmaf(s_vwl[a], ftanh(s_ql[a] + s_kt[a * TTXT + tid]),
                       partial);
      atomicAdd(&svp[(b & 7) * TTXT + tid], partial);  // 16-way contention
    }
    g_arrive(bar); ++bk;
    w0h_reg = red64(dot16load(s_w0 + wave * DIN, s_h, lane));  // deferred
    g_wait(bar, 16 * bk);

    // ---- Phase D: reduce score groups; dec LSTM0 gates via M --------------
    {
      if (tid < TTXT) {
        float s8 = aload(&svp[tid]);
#pragma unroll
        for (int g = 1; g < 8; ++g) s8 += aload(&svp[g * TTXT + tid]);
        s_sv[tid] = s8;
      }
      __syncthreads();
      float pa_ = __expf(s_sv[lane] - 16.f);        // scores bounded ~±11
      float pb_ = __expf(s_sv[lane + 64] - 16.f);
      float den_ = red64(pa_ + pb_);                // all lanes get den
      float w0c = red64(fmaf(pa_, s_m[wave * TTXT + lane],
                             pb_ * s_m[wave * TTXT + lane + 64]));
      if (lane == 0) s_red[wave] = w0c / den_ + w0h_reg + u0_reg + b0s;
      __syncthreads();
      if (tid < 4) {
        int ee = 4 * b + tid;
        float gi = s_red[tid * 4 + 0], gf = s_red[tid * 4 + 1];
        float gg = s_red[tid * 4 + 2], go = s_red[tid * 4 + 3];
        float c2 = sigm(gf) * c0_reg + sigm(gi) * ftanh(gg);
        c0_reg = c2;
        astore(&h0v[ee], sigm(go) * ftanh(c2));
      }
    }
    g_arrive(bar); ++bk;
    if (b == 0 && wave == 15) {  // deferred: gate output via Mg
      float pa_ = __expf(s_sv[lane] - 16.f);
      float pb_ = __expf(s_sv[lane + 64] - 16.f);
      float den_ = red64(pa_ + pb_);
      float gc = red64(fmaf(pa_, s_mg[lane], pb_ * s_mg[lane + 64]));
      if (lane == 0) {
        float gh = aload(&ghp[0]);
        p.out[T * MEL + t] = sigm(gh + gc / den_ + p.gate_b[0]);
      }
    }
    g_wait(bar, 16 * bk);

    // ---- Phase E: dec LSTM1 gates; re-zero svp; (u0' deferred) ------------
    s_h0[tid] = aload(h0v + tid);  // persists (used by deferred u0')
    __syncthreads();
    {
      float pe = dot16pin(wi0, wi1, wi2, wi3, s_h0, lane);
      pe = red64(pe);
      if (lane == 0) s_red[wave] = pe + u1_reg + b1s;
      __syncthreads();
      if (tid < 4) {
        int ee = 4 * b + tid;
        float gi = s_red[tid * 4 + 0], gf = s_red[tid * 4 + 1];
        float gg = s_red[tid * 4 + 2], go = s_red[tid * 4 + 3];
        float c2 = sigm(gf) * c1_reg + sigm(gi) * ftanh(gg);
        c1_reg = c2;
        astore(&h1v[ee], sigm(go) * ftanh(c2));
      }
    }
    if (b == NBLK - 1 && tid < 8 * TTXT)  // svp drained by D; next write B'(t+1)
      astore(&svp[tid], 0.f);
    g_arrive(bar); ++bk;
    u0_reg = red64(dot16pin(w00, w01, w02, w03, s_h0, lane));  // deferred
    g_wait(bar, 16 * bk);

    // ---- Phase F: a0 = tanh(D0w@h1 + b); (u1' for next step deferred) -----
    s_h1[tid] = aload(h1v + tid);
    __syncthreads();
    {
      float4 x = ((const float4*)s_h1)[wg * 64 + lane];
      float s = wf.x * x.x;
      s = fmaf(wf.y, x.y, s); s = fmaf(wf.z, x.z, s); s = fmaf(wf.w, x.w, s);
      s = red64(s);
      if (lane == 0) s_red[wave] = s;
      __syncthreads();
      if (tid < 4) {
        int r2 = 4 * b + tid;
        float tot = s_red[tid * 4] + s_red[tid * 4 + 1] + s_red[tid * 4 + 2] +
                    s_red[tid * 4 + 3];
        astore(&a0g[r2], ftanh(tot + p.D0b[r2]));
      }
    }
    g_arrive(bar); ++bk;
    u1_reg = red64(dot16pin(w10, w11, w12, w13, s_h1, lane));  // deferred
    g_wait(bar, 16 * bk);

    // ---- Phase G: d = tanh(D1w@a0 + b); conv partial into dec -------------
    s_a0[tid] = aload(a0g + tid);
    __syncthreads();
    {
      float4 x = ((const float4*)s_a0)[wg * 64 + lane];
      float s = wgd.x * x.x;
      s = fmaf(wgd.y, x.y, s); s = fmaf(wgd.z, x.z, s); s = fmaf(wgd.w, x.w, s);
      s = red64(s);
      if (lane == 0) s_red[wave] = s;
      __syncthreads();
      if (tid < 4) {
        int r2 = 4 * b + tid;
        float tot = s_red[tid * 4] + s_red[tid * 4 + 1] + s_red[tid * 4 + 2] +
                    s_red[tid * 4 + 3];
        s_d[tid] = ftanh(tot + p.D1b[r2]);
      }
      __syncthreads();
      if (tid < 2 * MEL) {
        float acc = wcv.x * s_d[0];
        acc = fmaf(wcv.y, s_d[1], acc);
        acc = fmaf(wcv.z, s_d[2], acc);
        acc = fmaf(wcv.w, s_d[3], acc);
        atomicAdd(&dec[tid], acc);
      }
    }
    g_arrive(bar); ++bk;
    g_wait(bar, 16 * bk);
  }

  // ---- epilogue: output for t = T-1 (total[0]) ----
  if (b == 0 && tid < MEL) {
    float ls = aload(&dec[tid]) + p.conv_b[tid];
    float bb = aload(&dec[MEL + tid]) + p.conv_b[MEL + tid];
    float r = p.residual[tid];
    p.out[tid] = (r - bb) * __expf(-ls);
  }
}

extern "C" void kernel_launch(void* const* d_in, const int* in_sizes, int n_in,
                              void* d_out, int out_size, void* d_ws, size_t ws_size,
                              hipStream_t stream) {
  Params hp;
  hp.residual = (const float*)d_in[0];
  hp.text = (const float*)d_in[1];
  hp.Wih_a = (const float*)d_in[2];
  hp.Whh_a = (const float*)d_in[3];
  hp.bih_a = (const float*)d_in[4];
  hp.bhh_a = (const float*)d_in[5];
  hp.Wq = (const float*)d_in[6];
  hp.Wk = (const float*)d_in[7];
  hp.Wv = (const float*)d_in[8];
  hp.v_w = (const float*)d_in[9];
  hp.Wih0 = (const float*)d_in[10];
  hp.Whh0 = (const float*)d_in[11];
  hp.bih0 = (const float*)d_in[12];
  hp.bhh0 = (const float*)d_in[13];
  hp.Wih1 = (const float*)d_in[14];
  hp.Whh1 = (const float*)d_in[15];
  hp.bih1 = (const float*)d_in[16];
  hp.bhh1 = (const float*)d_in[17];
  hp.D0w = (const float*)d_in[18];
  hp.D0b = (const float*)d_in[19];
  hp.D1w = (const float*)d_in[20];
  hp.D1b = (const float*)d_in[21];
  hp.conv_w = (const float*)d_in[22];
  hp.conv_b = (const float*)d_in[23];
  hp.gate_w = (const float*)d_in[24];
  hp.gate_b = (const float*)d_in[25];
  hp.out = (float*)d_out;
  hp.ws = (float*)d_ws;

  hipMemsetAsync((char*)d_ws + (size_t)WS_BAR * sizeof(float), 0, 4096, stream);

  void* args[] = {&hp};
  hipLaunchCooperativeKernel((void*)ar_kernel, dim3(NBLK), dim3(NTHR), args,
                             (uint32_t)SM_BYTES, stream);
}